// Round 3
// baseline (743.030 us; speedup 1.0000x reference)
//
#include <hip/hip_runtime.h>
#include <cstdint>
#include <cstddef>

#define D_MODEL 2048
#define D_FFN   8192
#define RANK    16
#define EPS     1e-6f
#define MOD_SCALE 0.1f

typedef float    f32x4 __attribute__((ext_vector_type(4)));
typedef _Float16 half8 __attribute__((ext_vector_type(8)));

// Async global->LDS, 16B per lane. LDS dest is wave-uniform base + lane*16;
// the GLOBAL address is per-lane, so we XOR-swizzle the source 16B chunk
// (c ^ (row&7)) for bank-conflict-free ds_read_b128 later, at zero cost.
// Proven conflict-free ONLY with the 16x16 quad-based fragment addressing
// (frag64 below). Geometry everywhere: 64-half (128 B) row stride.
__device__ __forceinline__ void async_load16(const void* g, void* l) {
  __builtin_amdgcn_global_load_lds(
      (const __attribute__((address_space(1))) uint32_t*)g,
      (__attribute__((address_space(3))) uint32_t*)l,
      16, 0, 0);
}

// Stage one 64-row x 64-half (8 KB) round; 512 threads x 16 B.
__device__ __forceinline__ void stage_round(const _Float16* __restrict__ g,
                                            size_t stride, _Float16* l, int tid) {
  const int row = tid >> 3;
  const int cs  = (tid & 7) ^ (row & 7);
  async_load16(g + (size_t)row * stride + (size_t)cs * 8, l + tid * 8);
}

// Read 8-half fragment at (row, 8-half chunk ck) from a swizzled 64-wide tile.
__device__ __forceinline__ half8 frag64(const _Float16* base, int row, int ck) {
  return *(const half8*)&base[row * 64 + ((ck ^ (row & 7)) * 8)];
}

#define PRIO1() __builtin_amdgcn_s_setprio(1)
#define PRIO0() __builtin_amdgcn_s_setprio(0)
#define VMW(n)  asm volatile("s_waitcnt vmcnt(" #n ")" ::: "memory")
#define LKW(n)  asm volatile("s_waitcnt lgkmcnt(" #n ")" ::: "memory")
// Raw barrier WITH compiler memory fence (no waitcnt drain emitted, unlike
// __syncthreads): no LDS/global op may be moved across it by the scheduler.
#define BARM()  asm volatile("s_barrier" ::: "memory")

// ---------------------------------------------------------------------------
// Fused fp32 -> f16 convert for all three big weights (one launch).
// ---------------------------------------------------------------------------
__global__ __launch_bounds__(256) void convert3_f32_f16(
    const float* __restrict__ s0, const float* __restrict__ s1,
    const float* __restrict__ s2,
    _Float16* __restrict__ d0, _Float16* __restrict__ d1,
    _Float16* __restrict__ d2)
{
  const int w = blockIdx.x >> 13;
  const float*   s = (w == 0) ? s0 : (w == 1) ? s1 : s2;
  _Float16*      d = (w == 0) ? d0 : (w == 1) ? d1 : d2;
  size_t i = ((size_t)(blockIdx.x & 8191) * 256 + threadIdx.x) * 8;
  f32x4 a = *(const f32x4*)(s + i);
  f32x4 b = *(const f32x4*)(s + i + 4);
  half8 h;
  #pragma unroll
  for (int j = 0; j < 4; ++j) { h[j] = (_Float16)a[j]; h[4+j] = (_Float16)b[j]; }
  *(half8*)(d + i) = h;
}

__global__ __launch_bounds__(256) void convert_f32_f16(
    const float* __restrict__ s, _Float16* __restrict__ d)
{
  size_t i = ((size_t)blockIdx.x * 256 + threadIdx.x) * 8;
  f32x4 a = *(const f32x4*)(s + i);
  f32x4 b = *(const f32x4*)(s + i + 4);
  half8 h;
  #pragma unroll
  for (int j = 0; j < 4; ++j) { h[j] = (_Float16)a[j]; h[4+j] = (_Float16)b[j]; }
  *(half8*)(d + i) = h;
}

// ---------------------------------------------------------------------------
// Kernel 1: per-token RMSNorm -> h (f16), c[m,r] = (h.A)[r] * 0.1*tanh((attn.A)[r])
// ---------------------------------------------------------------------------
__global__ __launch_bounds__(256) void prep_kernel(
    const float* __restrict__ hs, const float* __restrict__ attn,
    const float* __restrict__ Amat, const float* __restrict__ gamma,
    _Float16* __restrict__ h16, float* __restrict__ cmat)
{
  const int token = blockIdx.x;
  const int tid   = threadIdx.x;
  const int lane  = tid & 63;
  const int wv    = tid >> 6;
  const size_t tb = (size_t)token * D_MODEL;
  const int base  = tid * 8;

  f32x4 x0 = *(const f32x4*)(hs + tb + base);
  f32x4 x1 = *(const f32x4*)(hs + tb + base + 4);
  f32x4 a0 = *(const f32x4*)(attn + tb + base);
  f32x4 a1 = *(const f32x4*)(attn + tb + base + 4);

  float ss = 0.f;
  #pragma unroll
  for (int j = 0; j < 4; ++j) ss += x0[j]*x0[j] + x1[j]*x1[j];
  #pragma unroll
  for (int off = 32; off > 0; off >>= 1) ss += __shfl_xor(ss, off, 64);

  __shared__ float red[4];
  __shared__ float redp[4][RANK];
  __shared__ float redh[4][RANK];
  if (lane == 0) red[wv] = ss;
  __syncthreads();
  const float tot = red[0] + red[1] + red[2] + red[3];
  const float rms = rsqrtf(tot * (1.0f / D_MODEL) + EPS);

  f32x4 g0 = *(const f32x4*)(gamma + base);
  f32x4 g1 = *(const f32x4*)(gamma + base + 4);
  float hv[8], av[8];
  #pragma unroll
  for (int j = 0; j < 4; ++j) {
    hv[j]   = x0[j] * rms * g0[j];
    hv[4+j] = x1[j] * rms * g1[j];
    av[j]   = a0[j];
    av[4+j] = a1[j];
  }
  half8 hh;
  #pragma unroll
  for (int j = 0; j < 8; ++j) hh[j] = (_Float16)hv[j];
  *(half8*)(h16 + tb + base) = hh;

  float pa[RANK], ph[RANK];
  #pragma unroll
  for (int r = 0; r < RANK; ++r) { pa[r] = 0.f; ph[r] = 0.f; }
  #pragma unroll
  for (int e = 0; e < 8; ++e) {
    const f32x4* Ar = (const f32x4*)(Amat + (size_t)(base + e) * RANK);
    #pragma unroll
    for (int q = 0; q < 4; ++q) {
      f32x4 ar = Ar[q];
      #pragma unroll
      for (int j = 0; j < 4; ++j) {
        pa[q*4+j] += av[e] * ar[j];
        ph[q*4+j] += hv[e] * ar[j];
      }
    }
  }
  #pragma unroll
  for (int r = 0; r < RANK; ++r) {
    #pragma unroll
    for (int off = 32; off > 0; off >>= 1) {
      pa[r] += __shfl_xor(pa[r], off, 64);
      ph[r] += __shfl_xor(ph[r], off, 64);
    }
  }
  if (lane == 0) {
    #pragma unroll
    for (int r = 0; r < RANK; ++r) { redp[wv][r] = pa[r]; redh[wv][r] = ph[r]; }
  }
  __syncthreads();
  if (tid < RANK) {
    float sp = redp[0][tid] + redp[1][tid] + redp[2][tid] + redp[3][tid];
    float sh = redh[0][tid] + redh[1][tid] + redh[2][tid] + redh[3][tid];
    cmat[(size_t)token * RANK + tid] = sh * (MOD_SCALE * tanhf(sp));
  }
}

// ---------------------------------------------------------------------------
// MFMA / ds_read helper clusters (static indexing after unroll).
// ---------------------------------------------------------------------------
__device__ __forceinline__ void rdA(half8 (&d)[4][2], const _Float16* Ab,
                                    int lr, int quad) {
  #pragma unroll
  for (int im = 0; im < 4; ++im)
    #pragma unroll
    for (int kk = 0; kk < 2; ++kk)
      d[im][kk] = frag64(Ab, im*16 + lr, kk*4 + quad);
}
__device__ __forceinline__ void rdB(half8 (&d)[2][2], const _Float16* Bb,
                                    int lr, int quad) {
  #pragma unroll
  for (int inn = 0; inn < 2; ++inn)
    #pragma unroll
    for (int kk = 0; kk < 2; ++kk)
      d[inn][kk] = frag64(Bb, inn*16 + lr, kk*4 + quad);
}
__device__ __forceinline__ void cluster(f32x4 (&acc)[8][2], int base,
                                        const half8 (&a)[4][2],
                                        const half8 (&b)[2][2]) {
  #pragma unroll
  for (int im = 0; im < 4; ++im)
    #pragma unroll
    for (int inn = 0; inn < 2; ++inn)
      #pragma unroll
      for (int kk = 0; kk < 2; ++kk)
        acc[base+im][inn] = __builtin_amdgcn_mfma_f32_16x16x32_f16(
            a[im][kk], b[inn][kk], acc[base+im][inn], 0, 0, 0);
}

// ---------------------------------------------------------------------------
// Kernel 2: dual GEMM, 256x128 tile, BK=64, 8 waves (2M x 4N), m201-faithful
// 8-phase schedule: 2 K-tiles per iteration (STATIC buf0/buf1 addressing),
// one half-tile staged per phase, vmcnt(6) ONLY at phase 4/8 ends.
//
// Phase p: {ds_read this phase's frags; stage 1 half-tile; BAR; [lgkm by
// compiler]; setprio(1); 16 MFMA; setprio(0); BAR}. Overlap mechanism: waves
// pass BAR right after issuing reads; each waits lgkmcnt on its OWN reads;
// LDS serves waves staggered so early waves' MFMA covers late waves' service.
//
// Zigzag quadrant order per K-tile (reads 12/4/8/0):
//   p1: A_even x Bg (rd af,bg)  p2: A_even x Bu (rd bu)
//   p3: A_odd  x Bu (rd ao)     p4: A_odd  x Bg (rd none; bg held from p1)
// Stage slots (region frees: Bg@p1, A_even&Bu@p2, A_odd@p3):
//   p1: A_odd(2i+1)->buf1  p2: Bg(2i+2)->buf0  p3: Bu(2i+2)->buf0
//   p4: A_even(2i+2)->buf0 p5: A_odd(2i+2)->buf0 p6: Bg(2i+3)->buf1
//   p7: Bu(2i+3)->buf1     p8: A_even(2i+3)->buf1
// vmcnt audit (1 half-tile = 2 loads): entering p1 in-flight = {Bg,Bu,AE}(t1)
// = 6. p1-p4 add 8 -> 14; VMW(6) drains exactly tile t1's 4 halves (staged
// 3-7 phases ago -> wait is free). p5-p8 add 8 -> 14; VMW(6) drains tile
// t2's 4 halves, leaves {Bg,Bu,AE}(t3) = 6 = steady entry. Last iteration
// stages only p1 -> VMW(0) at p4/p8.
// ---------------------------------------------------------------------------
#define BGOFF 16384
#define BUOFF 24576

__global__ __launch_bounds__(512, 2) void gemm_gateup(
    const _Float16* __restrict__ h16,
    const _Float16* __restrict__ Wg16, const _Float16* __restrict__ Wu16,
    const float* __restrict__ cmat, const float* __restrict__ Bmat,
    _Float16* __restrict__ tmat)
{
  __shared__ __align__(16) _Float16 lds[2][32768];   // 128 KB

  const int tid  = threadIdx.x;
  const int lane = tid & 63;
  const int wv   = tid >> 6;          // 0..7
  const int lr   = lane & 15;
  const int quad = lane >> 4;
  const int qb   = (wv >> 2) * 2;     // A quarter base: 0 or 2 (even quarters)
  const int e    = wv & 3;            // B sub-tile (32 cols)
  const int wm   = (wv >> 2) * 128;   // wave row base in tile

  // XCD-partitioned mapping (native dispatch: lin%8 -> XCD):
  // xcd owns m-tiles {2*xcd, 2*xcd+1}; within-XCD order n-fast, m-pair inner.
  const int lin  = blockIdx.x;
  const int xcd  = lin & 7;
  const int r    = lin >> 3;                 // 0..127
  const int gm0  = (xcd * 2 + (r & 1)) * 256;
  const int gn0  = (r >> 1) * 128;

  f32x4 accG[8][2], accU[8][2];
  #pragma unroll
  for (int i = 0; i < 8; ++i)
    #pragma unroll
    for (int j = 0; j < 2; ++j) {
      f32x4 z = {0.f, 0.f, 0.f, 0.f};
      accG[i][j] = z; accU[i][j] = z;
    }

  // Half-tile stages (each = 2 stage_rounds = 2 vmcnt slots/thread).
  // A quarters: q at lds[b][q*4096], global rows gm0+q*64. Even = {q0,q2}.
#define STAE(b,t) do { \
    stage_round(h16 + (size_t)(gm0 +   0) * D_MODEL + (size_t)(t)*64, D_MODEL, &lds[b][0],     tid); \
    stage_round(h16 + (size_t)(gm0 + 128) * D_MODEL + (size_t)(t)*64, D_MODEL, &lds[b][8192],  tid); } while (0)
#define STAO(b,t) do { \
    stage_round(h16 + (size_t)(gm0 +  64) * D_MODEL + (size_t)(t)*64, D_MODEL, &lds[b][4096],  tid); \
    stage_round(h16 + (size_t)(gm0 + 192) * D_MODEL + (size_t)(t)*64, D_MODEL, &lds[b][12288], tid); } while (0)
#define STG(b,t) do { \
    stage_round(Wg16 + (size_t)(gn0 +  0) * D_MODEL + (size_t)(t)*64, D_MODEL, &lds[b][BGOFF],        tid); \
    stage_round(Wg16 + (size_t)(gn0 + 64) * D_MODEL + (size_t)(t)*64, D_MODEL, &lds[b][BGOFF + 4096], tid); } while (0)
#define STU(b,t) do { \
    stage_round(Wu16 + (size_t)(gn0 +  0) * D_MODEL + (size_t)(t)*64, D_MODEL, &lds[b][BUOFF],        tid); \
    stage_round(Wu16 + (size_t)(gn0 + 64) * D_MODEL + (size_t)(t)*64, D_MODEL, &lds[b][BUOFF + 4096], tid); } while (0)

  // 4-phase group over one K-tile in compile-time buffer BUF.
#define PH4(BUF, S1, S2, S3, S4, W4)                                       \
  {                                                                        \
    const _Float16* A_  = &lds[BUF][0];                                    \
    const _Float16* Bg_ = &lds[BUF][BGOFF + e * 2048];                     \
    const _Float16* Bu_ = &lds[BUF][BUOFF + e * 2048];                     \
    half8 af[4][2], ao[4][2], bg[2][2], bu[2][2];                          \
    rdA(af, A_ + qb * 4096, lr, quad);                                     \
    rdB(bg, Bg_, lr, quad);                                                \
    S1; LKW(8);                                                            \
    BARM(); PRIO1(); cluster(accG, 0, af, bg); PRIO0(); BARM();            \
    rdB(bu, Bu_, lr, quad);                                                \
    S2;                                                                    \
    BARM(); PRIO1(); cluster(accU, 0, af, bu); PRIO0(); BARM();            \
    rdA(ao, A_ + (qb + 1) * 4096, lr, quad);                               \
    S3;                                                                    \
    BARM(); PRIO1(); cluster(accU, 4, ao, bu); PRIO0(); BARM();            \
    S4;                                                                    \
    BARM(); PRIO1(); cluster(accG, 4, ao, bg); PRIO0();                    \
    W4; BARM();                                                            \
  }

  // Prologue: tile 0 complete + {Bg,Bu,A_even} of tile 1 -> steady pattern.
  STAE(0, 0); STAO(0, 0); STG(0, 0); STU(0, 0);
  STG(1, 1);  STU(1, 1);  STAE(1, 1);
  VMW(6); BARM();

  #pragma unroll 1
  for (int i = 0; i < 16; ++i) {
    const int t1 = 2*i + 1, t2 = 2*i + 2, t3 = 2*i + 3;
    const bool more = (i < 15);
    PH4(0,
        { STAO(1, t1); },
        { if (more) STG(0, t2); },
        { if (more) STU(0, t2); },
        { if (more) STAE(0, t2); },
        { if (more) { VMW(6); } else { VMW(0); } });
    PH4(1,
        { if (more) STAO(0, t2); },
        { if (more) STG(1, t3); },
        { if (more) STU(1, t3); },
        { if (more) STAE(1, t3); },
        { if (more) { VMW(6); } else { VMW(0); } });
  }

  // ---- rank-16 delta folded in as one zero-padded K=32 MFMA step into accG ----
  __syncthreads();   // full drain; loop is done
  _Float16* l0 = &lds[0][0];
  for (int i = tid; i < 8192; i += 512) {           // cbuf [256][32]
    int m = i >> 5, k = i & 31;
    l0[i] = (k < RANK) ? (_Float16)cmat[(size_t)(gm0 + m) * RANK + k] : (_Float16)0.f;
  }
  for (int i = tid; i < 4096; i += 512) {           // bbuf [128][32]
    int f = i >> 5, k = i & 31;
    l0[8192 + i] = (k < RANK) ? (_Float16)Bmat[(size_t)k * D_FFN + gn0 + f] : (_Float16)0.f;
  }
  __syncthreads();
  #pragma unroll
  for (int ai = 0; ai < 8; ++ai) {
    half8 cf = *(const half8*)&l0[(wm + ai*16 + lr) * 32 + quad * 8];
    #pragma unroll
    for (int inn = 0; inn < 2; ++inn) {
      half8 bd = *(const half8*)&l0[8192 + (e*32 + inn*16 + lr) * 32 + quad * 8];
      accG[ai][inn] = __builtin_amdgcn_mfma_f32_16x16x32_f16(cf, bd, accG[ai][inn], 0, 0, 0);
    }
  }

  // ---- Epilogue: t = silu(gate) * up ----
  #pragma unroll
  for (int ai = 0; ai < 8; ++ai)
    #pragma unroll
    for (int inn = 0; inn < 2; ++inn) {
      const int grow = gm0 + wm + ai*16 + quad*4;
      const int gcol = gn0 + e*32 + inn*16 + lr;
      #pragma unroll
      for (int rr = 0; rr < 4; ++rr) {
        float g = accG[ai][inn][rr];
        float u = accU[ai][inn][rr];
        float s = g / (1.0f + __expf(-g));
        tmat[(size_t)(grow + rr) * D_FFN + gcol] = (_Float16)(s * u);
      }
    }
#undef STAE
#undef STAO
#undef STG
#undef STU
#undef PH4
}

// ---------------------------------------------------------------------------
// Kernel 3: out = hidden_states + t @ Wd16^T (K=8192). 256x128 tile, BK=64,
// 3-buffer rotation, 2-ahead staging, ONE barrier + counted vmcnt(6) per
// K-step (stage(t+2) stays in flight across the barrier; never drained to 0
// while t+2<NT). XCD mapping: XCD x owns n-tiles {2x,2x+1} -> its 2 Wd-panels
// (4 MB) L2-resident; each tmat panel shared by its 2 concurrent n-blocks.
// Grid = exactly 256 blocks (1 per CU).
// ---------------------------------------------------------------------------
__global__ __launch_bounds__(512, 2) void gemm_down(
    const _Float16* __restrict__ tmat, const _Float16* __restrict__ Wd16,
    const float* __restrict__ hs, float* __restrict__ out)
{
  __shared__ __align__(16) _Float16 lds[3][24576];   // 144 KB: A 16K halves | B 8K halves

  const int tid  = threadIdx.x;
  const int lane = tid & 63;
  const int wv   = tid >> 6;
  const int lr   = lane & 15;
  const int quad = lane >> 4;
  const int qb   = (wv >> 2) * 2;
  const int e    = wv & 3;
  const int wm   = (wv >> 2) * 128;

  const int lin  = blockIdx.x;               // 256 blocks
  const int xcd  = lin & 7;
  const int r    = lin >> 3;                 // 0..31
  const int gn0  = (xcd * 2 + (r & 1)) * 128;
  const int gm0  = (r >> 1) * 256;

  constexpr int NT = D_FFN / 64;          // 128

  f32x4 acc[8][2];
  #pragma unroll
  for (int i = 0; i < 8; ++i)
    #pragma unroll
    for (int j = 0; j < 2; ++j) {
      f32x4 z = {0.f, 0.f, 0.f, 0.f};
      acc[i][j] = z;
    }

#define DSTA(b,q,t) stage_round(tmat + (size_t)(gm0 + (q)*64) * D_FFN + (size_t)(t)*64, D_FFN, &lds[b][(q)*4096], tid)
#define DSTB(b,p,t) stage_round(Wd16 + (size_t)(gn0 + (p)*64) * D_FFN + (size_t)(t)*64, D_FFN, &lds[b][16384 + (p)*4096], tid)
#define DSTAGE_ALL(b,t) do { DSTA(b,0,t); DSTA(b,1,t); DSTA(b,2,t); DSTA(b,3,t); \
                             DSTB(b,0,t); DSTB(b,1,t); } while (0)

  // Prologue: tiles 0,1; wait to 6 -> tile 0 landed, tile 1 in flight.
  DSTAGE_ALL(0, 0);
  DSTAGE_ALL(1, 1);
  VMW(6); BARM();

  int cur = 0;
  for (int t = 0; t < NT; ++t) {
    const _Float16* A = &lds[cur][0];
    const _Float16* B = &lds[cur][16384 + e * 2048];
    int nx2 = cur + 2; if (nx2 >= 3) nx2 -= 3;     // buffer for tile t+2

    // 2-ahead staging into a buffer whose old data (t-1) was consumed before
    // the previous BARM.
    if (t + 2 < NT) DSTAGE_ALL(nx2, t + 2);

    half8 bf[2][2], af[4][2];
    #pragma unroll
    for (int inn = 0; inn < 2; ++inn)
      #pragma unroll
      for (int kk = 0; kk < 2; ++kk)
        bf[inn][kk] = frag64(B, inn*16 + lr, kk*4 + quad);
    #pragma unroll
    for (int im = 0; im < 4; ++im)
      #pragma unroll
      for (int kk = 0; kk < 2; ++kk)
        af[im][kk] = frag64(A + (qb + 0) * 4096, im*16 + lr, kk*4 + quad);

    PRIO1();
    #pragma unroll
    for (int im = 0; im < 4; ++im)
      #pragma unroll
      for (int inn = 0; inn < 2; ++inn)
        #pragma unroll
        for (int kk = 0; kk < 2; ++kk)
          acc[im][inn] = __builtin_amdgcn_mfma_f32_16x16x32_f16(af[im][kk], bf[inn][kk], acc[im][inn], 0, 0, 0);
    PRIO0();

    half8 ao[4][2];
    #pragma unroll
    for (int im = 0; im < 4; ++im)
      #pragma unroll
      for (int kk = 0; kk < 2; ++kk)
        ao[im][kk] = frag64(A + (qb + 1) * 4096, im*16 + lr, kk*4 + quad);

    PRIO1();
    #pragma unroll
    for (int im = 0; im < 4; ++im)
      #pragma unroll
      for (int inn = 0; inn < 2; ++inn)
        #pragma unroll
        for (int kk = 0; kk < 2; ++kk)
          acc[4+im][inn] = __builtin_amdgcn_mfma_f32_16x16x32_f16(ao[im][kk], bf[inn][kk], acc[4+im][inn], 0, 0, 0);
    PRIO0();

    // Drain stage(t+1) (needed next step); keep stage(t+2) in flight.
    if (t + 2 < NT) { VMW(6); } else { VMW(0); }
    BARM();

    cur += 1; if (cur >= 3) cur -= 3;
  }

  #pragma unroll
  for (int ai = 0; ai < 8; ++ai)
    #pragma unroll
    for (int inn = 0; inn < 2; ++inn) {
      const int grow = gm0 + wm + ai*16 + quad*4;
      const int gcol = gn0 + e*32 + inn*16 + lr;
      #pragma unroll
      for (int rr = 0; rr < 4; ++rr) {
        size_t o = (size_t)(grow + rr) * D_MODEL + gcol;
        out[o] = hs[o] + acc[ai][inn][rr];
      }
    }
#undef DSTA
#undef DSTB
#undef DSTAGE_ALL
}

extern "C" void kernel_launch(void* const* d_in, const int* in_sizes, int n_in,
                              void* d_out, int out_size, void* d_ws, size_t ws_size,
                              hipStream_t stream) {
  const float* hs    = (const float*)d_in[0];
  const float* attn  = (const float*)d_in[1];
  const float* Amat  = (const float*)d_in[2];
  const float* Bmat  = (const float*)d_in[3];
  const float* Wg    = (const float*)d_in[4];
  const float* Wu    = (const float*)d_in[5];
  const float* Wd    = (const float*)d_in[6];
  const float* gamma = (const float*)d_in[7];
  float* out = (float*)d_out;

  const int M = in_sizes[0] / D_MODEL;        // 4096 tokens
  const size_t WD = (size_t)D_FFN * D_MODEL;  // elements per big weight

  char* ws = (char*)d_ws;
  _Float16* h16  = (_Float16*)ws;
  float*    cmat = (float*)(ws + (size_t)M * D_MODEL * 2);
  _Float16* tmat = (_Float16*)(ws + (size_t)M * D_MODEL * 2 + (size_t)M * RANK * 4);
  _Float16* wbuf = tmat + (size_t)M * D_FFN;
  _Float16* Wg16 = wbuf;
  _Float16* Wu16 = wbuf + WD;

  const size_t base_bytes = (size_t)M * D_MODEL * 2 + (size_t)M * RANK * 4
                          + (size_t)M * D_FFN * 2 + 2 * WD * 2;
  const bool sep_wd = (ws_size >= base_bytes + WD * 2);
  _Float16* Wd16 = sep_wd ? (wbuf + 2 * WD) : wbuf;   // else reuse Wg16 slot

  const int convBlocks = (int)(WD / (256 * 8));   // 8192 per weight

  prep_kernel<<<M, 256, 0, stream>>>(hs, attn, Amat, gamma, h16, cmat);
  if (sep_wd) {
    convert3_f32_f16<<<3 * convBlocks, 256, 0, stream>>>(Wg, Wu, Wd, Wg16, Wu16, Wd16);
    gemm_gateup<<<dim3((D_FFN / 128) * (M / 256)), 512, 0, stream>>>(h16, Wg16, Wu16, cmat, Bmat, tmat);
  } else {
    convert_f32_f16<<<convBlocks, 256, 0, stream>>>(Wg, Wg16);
    convert_f32_f16<<<convBlocks, 256, 0, stream>>>(Wu, Wu16);
    gemm_gateup<<<dim3((D_FFN / 128) * (M / 256)), 512, 0, stream>>>(h16, Wg16, Wu16, cmat, Bmat, tmat);
    convert_f32_f16<<<convBlocks, 256, 0, stream>>>(Wd, Wd16);
  }
  gemm_down<<<dim3((D_MODEL / 128) * (M / 256)), 512, 0, stream>>>(tmat, Wd16, hs, out);
}